// Round 1
// baseline (268.048 us; speedup 1.0000x reference)
//
#include <hip/hip_runtime.h>

typedef __attribute__((ext_vector_type(8))) short bf16x8;
typedef __attribute__((ext_vector_type(4))) float floatx4;

__device__ __forceinline__ unsigned short f2bf(float f) {
    unsigned int u = __float_as_uint(f);
    u += 0x7FFFu + ((u >> 16) & 1u);
    return (unsigned short)(u >> 16);
}

// ---- prep: x NCHW fp32 -> NHWC fp32 (coalesced channel reads in sampling) ----
__global__ __launch_bounds__(256) void prep_x(const float* __restrict__ x, float* __restrict__ xt) {
    int idx = blockIdx.x * 256 + threadIdx.x;   // idx = ((b*64+y)*64+xc)*64+c
    int c = idx & 63;
    int sp = idx >> 6;
    int xc = sp & 63;
    int rest = sp >> 6;
    int y = rest & 63;
    int b = rest >> 6;
    xt[idx] = x[((b * 64 + c) * 64 + y) * 64 + xc];
}

// ---- prep: W_off [18][64][3][3] -> [cin][tap][18] (contiguous over n for scalar loads) ----
__global__ __launch_bounds__(256) void prep_woff(const float* __restrict__ Woff, float* __restrict__ Wofft) {
    int idx = blockIdx.x * 256 + threadIdx.x;
    if (idx >= 18 * 64 * 9) return;             // 10368
    int n = idx % 18;
    int ct = idx / 18;
    int t = ct % 9;
    int cin = ct / 9;
    Wofft[idx] = Woff[(n * 64 + cin) * 9 + t];
}

// ---- prep: W_k [128][64][3][3] fp32 -> bf16 [oc][n*64+c] ----
__global__ __launch_bounds__(256) void prep_wk(const float* __restrict__ Wk, unsigned short* __restrict__ Wkb) {
    int idx = blockIdx.x * 256 + threadIdx.x;   // idx = oc*576 + n*64 + c
    int oc = idx / 576;
    int k = idx - oc * 576;
    int n = k >> 6;
    int c = k & 63;
    Wkb[idx] = f2bf(Wk[(oc * 64 + c) * 9 + n]);
}

// ---- offset conv: 3x3, pad 1, 64ch -> 18ch, fp32, LDS-tiled ----
__global__ __launch_bounds__(256) void offset_conv(const float* __restrict__ x,
        const float* __restrict__ Wofft, const float* __restrict__ boff,
        float* __restrict__ off) {
    __shared__ float xs[16 * 324];              // 16 ch chunk x 18x18 halo tile, 20.7 KB
    int tx = threadIdx.x & 15, ty = threadIdx.x >> 4;
    int tileX = blockIdx.x * 16, tileY = blockIdx.y * 16;
    int b = blockIdx.z;
    float acc[18];
#pragma unroll
    for (int n = 0; n < 18; n++) acc[n] = boff[n];
    for (int cc = 0; cc < 4; cc++) {
        __syncthreads();
        for (int i = threadIdx.x; i < 16 * 324; i += 256) {
            int c = i / 324;
            int rem = i - c * 324;
            int iy = rem / 18;
            int ix = rem - iy * 18;
            int gy = tileY + iy - 1, gx = tileX + ix - 1;
            float v = 0.f;
            if (gy >= 0 && gy < 64 && gx >= 0 && gx < 64)
                v = x[((b * 64 + cc * 16 + c) * 64 + gy) * 64 + gx];
            xs[i] = v;
        }
        __syncthreads();
        for (int c = 0; c < 16; c++) {
            const float* wc = Wofft + (cc * 16 + c) * 9 * 18;
#pragma unroll
            for (int t = 0; t < 9; t++) {
                int dy = t / 3, dx = t - (t / 3) * 3;
                float xv = xs[c * 324 + (ty + dy) * 18 + (tx + dx)];
#pragma unroll
                for (int n = 0; n < 18; n++)
                    acc[n] = fmaf(xv, wc[t * 18 + n], acc[n]);
            }
        }
    }
    int y = tileY + ty, xx = tileX + tx;
#pragma unroll
    for (int n = 0; n < 18; n++)
        off[((b * 18 + n) * 64 + y) * 64 + xx] = acc[n];
}

// ---- bilinear sampling: one wave per (pixel, tap), lane = channel ----
__global__ __launch_bounds__(256) void sample_kernel(const float* __restrict__ xt,
        const float* __restrict__ off, unsigned short* __restrict__ smp) {
    int wave = threadIdx.x >> 6;
    int lane = threadIdx.x & 63;
    int px = blockIdx.x * 4 + wave;             // b*4096 + y*64 + x
    int n = blockIdx.y;                         // tap 0..8
    int b = px >> 12;
    int yx = px & 4095;
    int y = yx >> 6;
    int xx = yx & 63;
    float orow = off[(b * 18 + n) * 4096 + yx];
    float ocol = off[(b * 18 + 9 + n) * 4096 + yx];
    float pr = (float)(y + (n / 3) - 1) + orow;
    float pc = (float)(xx + (n % 3) - 1) + ocol;
    pr = fminf(fmaxf(pr, 0.f), 63.f);
    pc = fminf(fmaxf(pc, 0.f), 63.f);
    float fr = floorf(pr), fc = floorf(pc);
    float tr = pr - fr, tc = pc - fc;
    int r0 = (int)fr, c0 = (int)fc;
    int r1 = min(r0 + 1, 63), c1 = min(c0 + 1, 63);
    const float* base = xt + b * 262144;        // NHWC image
    float v00 = base[(r0 * 64 + c0) * 64 + lane];
    float v01 = base[(r0 * 64 + c1) * 64 + lane];
    float v10 = base[(r1 * 64 + c0) * 64 + lane];
    float v11 = base[(r1 * 64 + c1) * 64 + lane];
    float val = (1.f - tr) * ((1.f - tc) * v00 + tc * v01)
              + tr * ((1.f - tc) * v10 + tc * v11);
    smp[(size_t)px * 576 + n * 64 + lane] = f2bf(val);
}

// ---- GEMM: out[px, oc] = W_kb[oc, 576] . smp[px, 576] + b_k[oc], bf16 MFMA ----
__global__ __launch_bounds__(256) void gemm_kernel(const unsigned short* __restrict__ A,
        const unsigned short* __restrict__ B, const float* __restrict__ bias,
        float* __restrict__ out) {
    __shared__ unsigned short As[128 * 32];     // [m=oc][k] 8 KB
    __shared__ unsigned short Bs[128 * 32];     // [n=px][k] 8 KB
    int tid = threadIdx.x;
    int wave = tid >> 6, lane = tid & 63;
    int pxBase = blockIdx.x * 128;
    int wm = wave & 1, wn = wave >> 1;          // wave -> (Mtile group, Ntile group)
    floatx4 acc[4][4];
#pragma unroll
    for (int i = 0; i < 4; i++)
#pragma unroll
        for (int j = 0; j < 4; j++)
            acc[i][j] = (floatx4)(0.f);

    int r = tid >> 2;                           // staging row 0..63
    int ke = (tid & 3) * 8;                     // k-element offset (x8 bf16 = 16B)

    for (int kc = 0; kc < 18; kc++) {           // K = 576 = 18 x 32
        __syncthreads();
#pragma unroll
        for (int half = 0; half < 2; half++) {
            int m = half * 64 + r;
            *(bf16x8*)&As[m * 32 + ke] =
                *(const bf16x8*)&A[m * 576 + kc * 32 + ke];
            *(bf16x8*)&Bs[m * 32 + ke] =
                *(const bf16x8*)&B[(size_t)(pxBase + m) * 576 + kc * 32 + ke];
        }
        __syncthreads();
        bf16x8 af[4], bfr[4];
        int frow = lane & 15, fk = (lane >> 4) * 8;
#pragma unroll
        for (int mt = 0; mt < 4; mt++)
            af[mt] = *(const bf16x8*)&As[(wm * 64 + mt * 16 + frow) * 32 + fk];
#pragma unroll
        for (int nt = 0; nt < 4; nt++)
            bfr[nt] = *(const bf16x8*)&Bs[(wn * 64 + nt * 16 + frow) * 32 + fk];
#pragma unroll
        for (int mt = 0; mt < 4; mt++)
#pragma unroll
            for (int nt = 0; nt < 4; nt++)
                acc[mt][nt] = __builtin_amdgcn_mfma_f32_16x16x32_bf16(
                    af[mt], bfr[nt], acc[mt][nt], 0, 0, 0);
    }

    int bimg = pxBase >> 12;
    float* outb = out + (size_t)bimg * 128 * 4096;
#pragma unroll
    for (int mt = 0; mt < 4; mt++) {
#pragma unroll
        for (int nt = 0; nt < 4; nt++) {
            int px = pxBase + wn * 64 + nt * 16 + (lane & 15);
            int yx = px & 4095;
#pragma unroll
            for (int rg = 0; rg < 4; rg++) {
                int oc = wm * 64 + mt * 16 + (lane >> 4) * 4 + rg;
                outb[oc * 4096 + yx] = acc[mt][nt][rg] + bias[oc];
            }
        }
    }
}

extern "C" void kernel_launch(void* const* d_in, const int* in_sizes, int n_in,
                              void* d_out, int out_size, void* d_ws, size_t ws_size,
                              hipStream_t stream) {
    const float* x    = (const float*)d_in[0];
    const float* Woff = (const float*)d_in[1];
    const float* boff = (const float*)d_in[2];
    const float* Wk   = (const float*)d_in[3];
    const float* bk   = (const float*)d_in[4];
    float* out = (float*)d_out;

    char* ws = (char*)d_ws;
    unsigned short* smp   = (unsigned short*)ws;                               // 65536*576*2 = 75497472 B
    float* xt             = (float*)(ws + 75497472);                           // 16777216 B
    float* offb           = (float*)(ws + 75497472 + 16777216);                // 4718592 B
    float* Wofft          = (float*)(ws + 75497472 + 16777216 + 4718592);      // 41472 B
    unsigned short* Wkb   = (unsigned short*)(ws + 75497472 + 16777216 + 4718592 + 41472); // 147456 B

    prep_x<<<16384, 256, 0, stream>>>(x, xt);
    prep_woff<<<41, 256, 0, stream>>>(Woff, Wofft);
    prep_wk<<<288, 256, 0, stream>>>(Wk, Wkb);
    offset_conv<<<dim3(4, 4, 16), 256, 0, stream>>>(x, Wofft, boff, offb);
    sample_kernel<<<dim3(16384, 9), 256, 0, stream>>>(xt, offb, smp);
    gemm_kernel<<<512, 256, 0, stream>>>(Wkb, smp, bk, out);
}

// Round 2
// 206.024 us; speedup vs baseline: 1.3011x; 1.3011x over previous
//
#include <hip/hip_runtime.h>

typedef __attribute__((ext_vector_type(8))) short bf16x8;
typedef __attribute__((ext_vector_type(4))) float floatx4;

__device__ __forceinline__ unsigned short f2bf(float f) {
    unsigned int u = __float_as_uint(f);
    u += 0x7FFFu + ((u >> 16) & 1u);
    return (unsigned short)(u >> 16);
}

__device__ __forceinline__ float rdlane_f(float v, int l) {
    return __uint_as_float((unsigned)__builtin_amdgcn_readlane(__float_as_uint(v), l));
}
__device__ __forceinline__ int rdlane_i(int v, int l) {
    return __builtin_amdgcn_readlane(v, l);
}

// ---- prep: x NCHW fp32 -> NHWC fp32, LDS-tiled transpose (both sides coalesced) ----
__global__ __launch_bounds__(256) void prep_x(const float* __restrict__ x, float* __restrict__ xt) {
    __shared__ float tile[64][65];
    int by = blockIdx.x;                 // b*64 + y
    int b = by >> 6, y = by & 63;
    const float* src = x + (size_t)b * 262144 + y * 64;   // + c*4096 + xc
    int tx = threadIdx.x & 15, tg = threadIdx.x >> 4;
#pragma unroll
    for (int i = 0; i < 4; i++) {
        int c = tg + i * 16;
        float4 v = *(const float4*)(src + (size_t)c * 4096 + tx * 4);
        tile[c][tx * 4 + 0] = v.x; tile[c][tx * 4 + 1] = v.y;
        tile[c][tx * 4 + 2] = v.z; tile[c][tx * 4 + 3] = v.w;
    }
    __syncthreads();
    float* dst = xt + (size_t)by * 4096; // [xc][c]
#pragma unroll
    for (int i = 0; i < 4; i++) {
        int xc = tg + i * 16;
        int c4 = tx * 4;
        float4 v = { tile[c4 + 0][xc], tile[c4 + 1][xc], tile[c4 + 2][xc], tile[c4 + 3][xc] };
        *(float4*)(dst + xc * 64 + c4) = v;
    }
}

// ---- prep: W_off [18][64][3][3] -> [cin][tap][18] ----
__global__ __launch_bounds__(256) void prep_woff(const float* __restrict__ Woff, float* __restrict__ Wofft) {
    int idx = blockIdx.x * 256 + threadIdx.x;
    if (idx >= 18 * 64 * 9) return;
    int n = idx % 18;
    int ct = idx / 18;
    int t = ct % 9;
    int cin = ct / 9;
    Wofft[idx] = Woff[(n * 64 + cin) * 9 + t];
}

// ---- prep: W_k [128][64][3][3] fp32 -> bf16 [oc][tap*64+c] ----
__global__ __launch_bounds__(256) void prep_wk(const float* __restrict__ Wk, unsigned short* __restrict__ Wkb) {
    int idx = blockIdx.x * 256 + threadIdx.x;   // idx = oc*576 + n*64 + c
    int oc = idx / 576;
    int k = idx - oc * 576;
    int n = k >> 6;
    int c = k & 63;
    Wkb[idx] = f2bf(Wk[(oc * 64 + c) * 9 + n]);
}

// ---- offset conv: 3x3, pad 1, 64ch -> 18ch, fp32, LDS-tiled ----
__global__ __launch_bounds__(256) void offset_conv(const float* __restrict__ x,
        const float* __restrict__ Wofft, const float* __restrict__ boff,
        float* __restrict__ off) {
    __shared__ float xs[16 * 324];
    int tx = threadIdx.x & 15, ty = threadIdx.x >> 4;
    int tileX = blockIdx.x * 16, tileY = blockIdx.y * 16;
    int b = blockIdx.z;
    float acc[18];
#pragma unroll
    for (int n = 0; n < 18; n++) acc[n] = boff[n];
    for (int cc = 0; cc < 4; cc++) {
        __syncthreads();
        for (int i = threadIdx.x; i < 16 * 324; i += 256) {
            int c = i / 324;
            int rem = i - c * 324;
            int iy = rem / 18;
            int ix = rem - iy * 18;
            int gy = tileY + iy - 1, gx = tileX + ix - 1;
            float v = 0.f;
            if (gy >= 0 && gy < 64 && gx >= 0 && gx < 64)
                v = x[((b * 64 + cc * 16 + c) * 64 + gy) * 64 + gx];
            xs[i] = v;
        }
        __syncthreads();
        for (int c = 0; c < 16; c++) {
            const float* wc = Wofft + (cc * 16 + c) * 9 * 18;
#pragma unroll
            for (int t = 0; t < 9; t++) {
                int dy = t / 3, dx = t - (t / 3) * 3;
                float xv = xs[c * 324 + (ty + dy) * 18 + (tx + dx)];
#pragma unroll
                for (int n = 0; n < 18; n++)
                    acc[n] = fmaf(xv, wc[t * 18 + n], acc[n]);
            }
        }
    }
    int y = tileY + ty, xx = tileX + tx;
#pragma unroll
    for (int n = 0; n < 18; n++)
        off[((b * 18 + n) * 64 + y) * 64 + xx] = acc[n];
}

// ---- fused bilinear-sample + GEMM ----
// out[px, oc] = sum_{tap,c} Wkb[oc, tap*64+c] * bilin(x, px, tap)[c] + bias[oc]
// block: 128 px x 128 oc, 4 waves (2x2), loop over 9 taps (K-chunks of 64)
__global__ __launch_bounds__(256) void fused_kernel(
        const float* __restrict__ xt,            // [b][y][x][c] fp32
        const float* __restrict__ off,           // [b][18][64][64]
        const unsigned short* __restrict__ Wkb,  // [oc][tap*64+c] bf16
        const float* __restrict__ bias,
        float* __restrict__ out) {
    __shared__ unsigned short As[128 * 72];      // [oc][k] pad->2-way banks, 18.4 KB
    __shared__ unsigned short Bs[128 * 72];      // [px][c] pad->2-way banks, 18.4 KB

    int tid = threadIdx.x;
    int wave = tid >> 6, lane = tid & 63;
    int wm = wave & 1, wn = wave >> 1;
    int pxBase = blockIdx.x * 128;
    int b = pxBase >> 12;
    const float* img = xt + (size_t)b * 262144;
    const float* offb = off + (size_t)b * 18 * 4096;
    const char* ibase = (const char*)img + lane * 4;   // lane = channel

    floatx4 acc[4][4];
#pragma unroll
    for (int i = 0; i < 4; i++)
#pragma unroll
        for (int j = 0; j < 4; j++)
            acc[i][j] = (floatx4)(0.f);

    int frow = lane & 15, fk = (lane >> 4) * 8;

    for (int tap = 0; tap < 9; tap++) {
        __syncthreads();   // previous iteration's MFMA reads complete before restage

        // --- stage As: 128 oc x 64 k bf16 slice of Wkb ---
        {
            int oc = tid >> 1, kh = (tid & 1) * 32;
            const unsigned short* srcw = Wkb + oc * 576 + tap * 64 + kh;
            unsigned short* dstw = As + oc * 72 + kh;
#pragma unroll
            for (int i = 0; i < 4; i++)
                *(bf16x8*)(dstw + i * 8) = *(const bf16x8*)(srcw + i * 8);
        }

        // --- phase 1: lane p computes bilinear weights/offsets for pixel wave*32+p
        //     (lanes 32-63 duplicate 0-31: no divergence, readlane always valid) ---
        float w00, w01, w10, w11;
        int o00, o01, o10, o11;
        {
            int p = lane & 31;
            int yx = (pxBase + wave * 32 + p) & 4095;
            int y = yx >> 6, xx = yx & 63;
            float orow = offb[tap * 4096 + yx];
            float ocol = offb[(9 + tap) * 4096 + yx];
            float pr = (float)(y + tap / 3 - 1) + orow;
            float pc = (float)(xx + tap % 3 - 1) + ocol;
            pr = fminf(fmaxf(pr, 0.f), 63.f);
            pc = fminf(fmaxf(pc, 0.f), 63.f);
            float fr = floorf(pr), fc = floorf(pc);
            float tr = pr - fr, tc = pc - fc;
            int r0 = (int)fr, c0 = (int)fc;
            int r1 = min(r0 + 1, 63), c1 = min(c0 + 1, 63);
            w00 = (1.f - tr) * (1.f - tc);
            w01 = (1.f - tr) * tc;
            w10 = tr * (1.f - tc);
            w11 = tr * tc;
            o00 = (r0 * 64 + c0) * 256;   // byte offset of corner (channel 0)
            o01 = (r0 * 64 + c1) * 256;
            o10 = (r1 * 64 + c0) * 256;
            o11 = (r1 * 64 + c1) * 256;
        }

        // --- phase 2: sample 32 px x 64 ch into Bs (lane = channel) ---
        {
            unsigned short* brow = Bs + (wave * 32) * 72 + lane;
#pragma unroll 8
            for (int p = 0; p < 32; p++) {
                float a00 = rdlane_f(w00, p), a01 = rdlane_f(w01, p);
                float a10 = rdlane_f(w10, p), a11 = rdlane_f(w11, p);
                int   q00 = rdlane_i(o00, p), q01 = rdlane_i(o01, p);
                int   q10 = rdlane_i(o10, p), q11 = rdlane_i(o11, p);
                float v00 = *(const float*)(ibase + q00);
                float v01 = *(const float*)(ibase + q01);
                float v10 = *(const float*)(ibase + q10);
                float v11 = *(const float*)(ibase + q11);
                float v = a00 * v00 + a01 * v01 + a10 * v10 + a11 * v11;
                brow[p * 72] = f2bf(v);
            }
        }
        __syncthreads();

        // --- MFMA: 2 k-steps of 32 over this tap's 64-wide slice ---
#pragma unroll
        for (int kc = 0; kc < 2; kc++) {
            bf16x8 af[4], bf[4];
#pragma unroll
            for (int mt = 0; mt < 4; mt++)
                af[mt] = *(const bf16x8*)&As[(wm * 64 + mt * 16 + frow) * 72 + kc * 32 + fk];
#pragma unroll
            for (int nt = 0; nt < 4; nt++)
                bf[nt] = *(const bf16x8*)&Bs[(wn * 64 + nt * 16 + frow) * 72 + kc * 32 + fk];
#pragma unroll
            for (int mt = 0; mt < 4; mt++)
#pragma unroll
                for (int nt = 0; nt < 4; nt++)
                    acc[mt][nt] = __builtin_amdgcn_mfma_f32_16x16x32_bf16(
                        af[mt], bf[nt], acc[mt][nt], 0, 0, 0);
        }
    }

    // --- epilogue: D layout col=lane&15 (px), row=(lane>>4)*4+rg (oc) ---
    float* outb = out + (size_t)b * 128 * 4096;
#pragma unroll
    for (int mt = 0; mt < 4; mt++) {
#pragma unroll
        for (int nt = 0; nt < 4; nt++) {
            int px = pxBase + wn * 64 + nt * 16 + (lane & 15);
            int yx = px & 4095;
#pragma unroll
            for (int rg = 0; rg < 4; rg++) {
                int oc = wm * 64 + mt * 16 + (lane >> 4) * 4 + rg;
                outb[oc * 4096 + yx] = acc[mt][nt][rg] + bias[oc];
            }
        }
    }
}

extern "C" void kernel_launch(void* const* d_in, const int* in_sizes, int n_in,
                              void* d_out, int out_size, void* d_ws, size_t ws_size,
                              hipStream_t stream) {
    const float* x    = (const float*)d_in[0];
    const float* Woff = (const float*)d_in[1];
    const float* boff = (const float*)d_in[2];
    const float* Wk   = (const float*)d_in[3];
    const float* bk   = (const float*)d_in[4];
    float* out = (float*)d_out;

    char* ws = (char*)d_ws;
    float* xt           = (float*)ws;                                  // 16777216 B
    float* offb         = (float*)(ws + 16777216);                     // 4718592 B
    float* Wofft        = (float*)(ws + 16777216 + 4718592);           // 41472 B
    unsigned short* Wkb = (unsigned short*)(ws + 16777216 + 4718592 + 41472); // 147456 B

    prep_x<<<1024, 256, 0, stream>>>(x, xt);
    prep_woff<<<41, 256, 0, stream>>>(Woff, Wofft);
    prep_wk<<<288, 256, 0, stream>>>(Wk, Wkb);
    offset_conv<<<dim3(4, 4, 16), 256, 0, stream>>>(x, Wofft, boff, offb);
    fused_kernel<<<512, 256, 0, stream>>>(xt, offb, Wkb, bk, out);
}

// Round 3
// 168.965 us; speedup vs baseline: 1.5864x; 1.2193x over previous
//
#include <hip/hip_runtime.h>

typedef __attribute__((ext_vector_type(8))) short bf16x8;
typedef __attribute__((ext_vector_type(4))) float floatx4;

__device__ __forceinline__ unsigned short f2bf(float f) {
    unsigned int u = __float_as_uint(f);
    u += 0x7FFFu + ((u >> 16) & 1u);
    return (unsigned short)(u >> 16);
}

__device__ __forceinline__ float rdlane_f(float v, int l) {
    return __uint_as_float((unsigned)__builtin_amdgcn_readlane(__float_as_uint(v), l));
}
__device__ __forceinline__ int rdlane_i(int v, int l) {
    return __builtin_amdgcn_readlane(v, l);
}

// ---- prep: x NCHW fp32 -> NHWC fp32, LDS-tiled transpose (both sides coalesced) ----
__global__ __launch_bounds__(256) void prep_x(const float* __restrict__ x, float* __restrict__ xt) {
    __shared__ float tile[64][65];
    int by = blockIdx.x;                 // b*64 + y
    int b = by >> 6, y = by & 63;
    const float* src = x + (size_t)b * 262144 + y * 64;   // + c*4096 + xc
    int tx = threadIdx.x & 15, tg = threadIdx.x >> 4;
#pragma unroll
    for (int i = 0; i < 4; i++) {
        int c = tg + i * 16;
        float4 v = *(const float4*)(src + (size_t)c * 4096 + tx * 4);
        tile[c][tx * 4 + 0] = v.x; tile[c][tx * 4 + 1] = v.y;
        tile[c][tx * 4 + 2] = v.z; tile[c][tx * 4 + 3] = v.w;
    }
    __syncthreads();
    float* dst = xt + (size_t)by * 4096; // [xc][c]
#pragma unroll
    for (int i = 0; i < 4; i++) {
        int xc = tg + i * 16;
        int c4 = tx * 4;
        float4 v = { tile[c4 + 0][xc], tile[c4 + 1][xc], tile[c4 + 2][xc], tile[c4 + 3][xc] };
        *(float4*)(dst + xc * 64 + c4) = v;
    }
}

// ---- prep: W_off [18][64][3][3] -> [cin][tap][18] ----
__global__ __launch_bounds__(256) void prep_woff(const float* __restrict__ Woff, float* __restrict__ Wofft) {
    int idx = blockIdx.x * 256 + threadIdx.x;
    if (idx >= 18 * 64 * 9) return;
    int n = idx % 18;
    int ct = idx / 18;
    int t = ct % 9;
    int cin = ct / 9;
    Wofft[idx] = Woff[(n * 64 + cin) * 9 + t];
}

// ---- prep: W_k [128][64][3][3] fp32 -> bf16 [oc][tap*64+c] ----
__global__ __launch_bounds__(256) void prep_wk(const float* __restrict__ Wk, unsigned short* __restrict__ Wkb) {
    int idx = blockIdx.x * 256 + threadIdx.x;   // idx = oc*576 + n*64 + c
    int oc = idx / 576;
    int k = idx - oc * 576;
    int n = k >> 6;
    int c = k & 63;
    Wkb[idx] = f2bf(Wk[(oc * 64 + c) * 9 + n]);
}

// ---- offset conv partials: 16-ch chunk per block, 1024 blocks for occupancy ----
__global__ __launch_bounds__(256) void offset_conv_part(const float* __restrict__ x,
        const float* __restrict__ Wofft, float* __restrict__ part) {
    __shared__ float xs[16 * 324];              // 16 ch x 18x18 halo, 20.7 KB
    int tx = threadIdx.x & 15, ty = threadIdx.x >> 4;
    int tileX = blockIdx.x * 16, tileY = blockIdx.y * 16;
    int bz = blockIdx.z;                        // b*4 + cc
    int b = bz >> 2, cc = bz & 3;
    float acc[18];
#pragma unroll
    for (int n = 0; n < 18; n++) acc[n] = 0.f;
    for (int i = threadIdx.x; i < 16 * 324; i += 256) {
        int c = i / 324;
        int rem = i - c * 324;
        int iy = rem / 18;
        int ix = rem - iy * 18;
        int gy = tileY + iy - 1, gx = tileX + ix - 1;
        float v = 0.f;
        if (gy >= 0 && gy < 64 && gx >= 0 && gx < 64)
            v = x[((b * 64 + cc * 16 + c) * 64 + gy) * 64 + gx];
        xs[i] = v;
    }
    __syncthreads();
    for (int c = 0; c < 16; c++) {
        const float* wc = Wofft + (cc * 16 + c) * 9 * 18;
#pragma unroll
        for (int t = 0; t < 9; t++) {
            int dy = t / 3, dx = t - (t / 3) * 3;
            float xv = xs[c * 324 + (ty + dy) * 18 + (tx + dx)];
#pragma unroll
            for (int n = 0; n < 18; n++)
                acc[n] = fmaf(xv, wc[t * 18 + n], acc[n]);
        }
    }
    int y = tileY + ty, xx = tileX + tx;
    float* dst = part + (size_t)cc * (16 * 18 * 4096) + (size_t)b * 18 * 4096 + y * 64 + xx;
#pragma unroll
    for (int n = 0; n < 18; n++)
        dst[n * 4096] = acc[n];
}

// ---- reduce 4 chunk-partials + bias -> off ----
__global__ __launch_bounds__(256) void offset_reduce(const float* __restrict__ part,
        const float* __restrict__ boff, float* __restrict__ off) {
    int idx = (blockIdx.x * 256 + threadIdx.x) * 4;   // over 16*18*4096 floats
    const size_t CH = (size_t)16 * 18 * 4096;
    float4 s0 = *(const float4*)(part + idx);
    float4 s1 = *(const float4*)(part + CH + idx);
    float4 s2 = *(const float4*)(part + 2 * CH + idx);
    float4 s3 = *(const float4*)(part + 3 * CH + idx);
    int n = (idx >> 12) % 18;
    float bv = boff[n];
    float4 r;
    r.x = s0.x + s1.x + s2.x + s3.x + bv;
    r.y = s0.y + s1.y + s2.y + s3.y + bv;
    r.z = s0.z + s1.z + s2.z + s3.z + bv;
    r.w = s0.w + s1.w + s2.w + s3.w + bv;
    *(float4*)(off + idx) = r;
}

// ---- fused bilinear-sample + GEMM ----
// out[px, oc] = sum_{tap,c} Wkb[oc, tap*64+c] * bilin(x, px, tap)[c] + bias[oc]
// block: 128 px x 128 oc, 4 waves (2x2), loop over 9 taps (K-chunks of 64)
__global__ __launch_bounds__(256) void fused_kernel(
        const float* __restrict__ xt,            // [b][y][x][c] fp32
        const float* __restrict__ off,           // [b][18][64][64]
        const unsigned short* __restrict__ Wkb,  // [oc][tap*64+c] bf16
        const float* __restrict__ bias,
        float* __restrict__ out) {
    __shared__ unsigned short As[128 * 72];      // [oc][k] pad->2-way banks, 18.4 KB
    __shared__ unsigned short Bs[128 * 72];      // [px][c] pad->2-way banks, 18.4 KB

    int tid = threadIdx.x;
    int wave = tid >> 6, lane = tid & 63;
    int wm = wave & 1, wn = wave >> 1;
    int pxBase = blockIdx.x * 128;
    int b = pxBase >> 12;
    const float* img = xt + (size_t)b * 262144;
    const float* offb = off + (size_t)b * 18 * 4096;
    const char* ibase = (const char*)img + lane * 4;   // lane = channel

    floatx4 acc[4][4];
#pragma unroll
    for (int i = 0; i < 4; i++)
#pragma unroll
        for (int j = 0; j < 4; j++)
            acc[i][j] = (floatx4)(0.f);

    int frow = lane & 15, fk = (lane >> 4) * 8;

    for (int tap = 0; tap < 9; tap++) {
        __syncthreads();   // previous iteration's MFMA reads complete before restage

        // --- stage As: 128 oc x 64 k bf16 slice of Wkb ---
        {
            int oc = tid >> 1, kh = (tid & 1) * 32;
            const unsigned short* srcw = Wkb + oc * 576 + tap * 64 + kh;
            unsigned short* dstw = As + oc * 72 + kh;
#pragma unroll
            for (int i = 0; i < 4; i++)
                *(bf16x8*)(dstw + i * 8) = *(const bf16x8*)(srcw + i * 8);
        }

        // --- phase 1: lane p computes bilinear weights/offsets for pixel wave*32+p ---
        float w00, w01, w10, w11;
        int o00, o01, o10, o11;
        {
            int p = lane & 31;
            int yx = (pxBase + wave * 32 + p) & 4095;
            int y = yx >> 6, xx = yx & 63;
            float orow = offb[tap * 4096 + yx];
            float ocol = offb[(9 + tap) * 4096 + yx];
            float pr = (float)(y + tap / 3 - 1) + orow;
            float pc = (float)(xx + tap % 3 - 1) + ocol;
            pr = fminf(fmaxf(pr, 0.f), 63.f);
            pc = fminf(fmaxf(pc, 0.f), 63.f);
            float fr = floorf(pr), fc = floorf(pc);
            float tr = pr - fr, tc = pc - fc;
            int r0 = (int)fr, c0 = (int)fc;
            int r1 = min(r0 + 1, 63), c1 = min(c0 + 1, 63);
            w00 = (1.f - tr) * (1.f - tc);
            w01 = (1.f - tr) * tc;
            w10 = tr * (1.f - tc);
            w11 = tr * tc;
            o00 = (r0 * 64 + c0) * 256;   // byte offset of corner (channel 0)
            o01 = (r0 * 64 + c1) * 256;
            o10 = (r1 * 64 + c0) * 256;
            o11 = (r1 * 64 + c1) * 256;
        }

        // --- phase 2: sample 32 px x 64 ch into Bs (lane = channel) ---
        {
            unsigned short* brow = Bs + (wave * 32) * 72 + lane;
#pragma unroll 8
            for (int p = 0; p < 32; p++) {
                float a00 = rdlane_f(w00, p), a01 = rdlane_f(w01, p);
                float a10 = rdlane_f(w10, p), a11 = rdlane_f(w11, p);
                int   q00 = rdlane_i(o00, p), q01 = rdlane_i(o01, p);
                int   q10 = rdlane_i(o10, p), q11 = rdlane_i(o11, p);
                float v00 = *(const float*)(ibase + q00);
                float v01 = *(const float*)(ibase + q01);
                float v10 = *(const float*)(ibase + q10);
                float v11 = *(const float*)(ibase + q11);
                float v = a00 * v00 + a01 * v01 + a10 * v10 + a11 * v11;
                brow[p * 72] = f2bf(v);
            }
        }
        __syncthreads();

        // --- MFMA: 2 k-steps of 32 over this tap's 64-wide slice ---
#pragma unroll
        for (int kc = 0; kc < 2; kc++) {
            bf16x8 af[4], bf[4];
#pragma unroll
            for (int mt = 0; mt < 4; mt++)
                af[mt] = *(const bf16x8*)&As[(wm * 64 + mt * 16 + frow) * 72 + kc * 32 + fk];
#pragma unroll
            for (int nt = 0; nt < 4; nt++)
                bf[nt] = *(const bf16x8*)&Bs[(wn * 64 + nt * 16 + frow) * 72 + kc * 32 + fk];
#pragma unroll
            for (int mt = 0; mt < 4; mt++)
#pragma unroll
                for (int nt = 0; nt < 4; nt++)
                    acc[mt][nt] = __builtin_amdgcn_mfma_f32_16x16x32_bf16(
                        af[mt], bf[nt], acc[mt][nt], 0, 0, 0);
        }
    }

    // --- epilogue: D layout col=lane&15 (px), row=(lane>>4)*4+rg (oc) ---
    float* outb = out + (size_t)b * 128 * 4096;
#pragma unroll
    for (int mt = 0; mt < 4; mt++) {
#pragma unroll
        for (int nt = 0; nt < 4; nt++) {
            int px = pxBase + wn * 64 + nt * 16 + (lane & 15);
            int yx = px & 4095;
#pragma unroll
            for (int rg = 0; rg < 4; rg++) {
                int oc = wm * 64 + mt * 16 + (lane >> 4) * 4 + rg;
                outb[oc * 4096 + yx] = acc[mt][nt][rg] + bias[oc];
            }
        }
    }
}

extern "C" void kernel_launch(void* const* d_in, const int* in_sizes, int n_in,
                              void* d_out, int out_size, void* d_ws, size_t ws_size,
                              hipStream_t stream) {
    const float* x    = (const float*)d_in[0];
    const float* Woff = (const float*)d_in[1];
    const float* boff = (const float*)d_in[2];
    const float* Wk   = (const float*)d_in[3];
    const float* bk   = (const float*)d_in[4];
    float* out = (float*)d_out;

    char* ws = (char*)d_ws;
    float* xt           = (float*)ws;                                  // 16777216 B
    float* offb         = (float*)(ws + 16777216);                     // 4718592 B
    float* Wofft        = (float*)(ws + 16777216 + 4718592);           // 41472 B
    unsigned short* Wkb = (unsigned short*)(ws + 21537280);            // 147456 B
    float* part         = (float*)(ws + 21684736);                     // 4*16*18*4096*4 = 18874368 B

    prep_x<<<1024, 256, 0, stream>>>(x, xt);
    prep_woff<<<41, 256, 0, stream>>>(Woff, Wofft);
    prep_wk<<<288, 256, 0, stream>>>(Wk, Wkb);
    offset_conv_part<<<dim3(4, 4, 64), 256, 0, stream>>>(x, Wofft, part);
    offset_reduce<<<1152, 256, 0, stream>>>(part, boff, offb);
    fused_kernel<<<512, 256, 0, stream>>>(xt, offb, Wkb, bk, out);
}